// Round 5
// baseline (190.909 us; speedup 1.0000x reference)
//
#include <hip/hip_runtime.h>

typedef unsigned short ushort_t;
typedef __attribute__((ext_vector_type(8))) short s8v;      // 8 bf16 bits = MFMA A/B frag
typedef __attribute__((ext_vector_type(2))) unsigned u2v;   // packed 4 bf16 (8B LDS write)
typedef __attribute__((ext_vector_type(4))) float f4;       // float4 / MFMA C/D frag

__device__ __forceinline__ ushort_t f2bf(float x) {      // RNE fp32->bf16
    unsigned u = __builtin_bit_cast(unsigned, x);
    return (ushort_t)((u + 0x7FFFu + ((u >> 16) & 1u)) >> 16);
}
__device__ __forceinline__ unsigned pack_hi16(float lo, float hi) {  // {bf16(hi),bf16(lo)} trunc
    unsigned a = __builtin_bit_cast(unsigned, lo);
    unsigned b = __builtin_bit_cast(unsigned, hi);
    return (a >> 16) | (b & 0xFFFF0000u);
}

// ---- fused pre-pass: blocks 0..2047 K-convert, 2048..3071 V-transpose (unchanged) ----
__global__ __launch_bounds__(256) void prep_kv(const float* __restrict__ K,
                                               const float* __restrict__ V,
                                               ushort_t* __restrict__ Kb,
                                               ushort_t* __restrict__ VT) {
    __shared__ ushort_t T[64 * 72];
    if (blockIdx.x < 2048) {
        const int gid = blockIdx.x * 256 + threadIdx.x;
        const int e = (gid & 7) * 8;
        const int h = (gid >> 3) & 15;
        const int s = (gid >> 7) & 2047;
        const int b = gid >> 18;
        const float* src = K + (((b * 2048 + s) * 16 + h) * 64 + e);
        f4 a = *(const f4*)src;
        f4 c = *(const f4*)(src + 4);
        s8v o;
        #pragma unroll
        for (int j = 0; j < 4; ++j) { o[j] = (short)f2bf(a[j]); o[j + 4] = (short)f2bf(c[j]); }
        *(s8v*)(Kb + (((b * 16 + h) * 2048 + s) * 64 + e)) = o;
    } else {
        const int v = blockIdx.x - 2048;
        const int s0 = (v & 31) * 64;
        const int h  = (v >> 5) & 15;
        const int b  = v >> 9;
        const int t  = threadIdx.x;
        {
            const int srow = t >> 2, dc = (t & 3) * 16;
            const float* src = V + (((b * 2048 + s0 + srow) * 16 + h) * 64 + dc);
            #pragma unroll
            for (int c = 0; c < 4; ++c) {
                f4 vv = *(const f4*)(src + c * 4);
                #pragma unroll
                for (int j = 0; j < 4; ++j) T[(dc + c * 4 + j) * 72 + srow] = f2bf(vv[j]);
            }
        }
        __syncthreads();
        {
            const int d = t >> 2, sq = (t & 3) * 16;
            ushort_t* dst = VT + (((b * 16 + h) * 64 + d) * 2048 + s0 + sq);
            *(s8v*)(dst)     = *(const s8v*)(&T[d * 72 + sq]);
            *(s8v*)(dst + 8) = *(const s8v*)(&T[d * 72 + sq + 8]);
        }
    }
}

// ---------------- main: 8-wave / 256-row q-tile / m=2 — LDS-traffic-minimal ----------
// Evidence (R0-R4): the binding resource is the LDS pipe. R1 (m=1, 8 w/CU):
// ~88 b128/block-iter -> ~41us LDS-busy of 55us wall (75% util incl 5.9M conflict
// cycles). m=2 (32 q-rows/wave) halves K/V re-reads per unit work but R2 showed
// 4 waves/CU is latency-bound (80us). 65536 q-rows / 32 = 2048 waves = 256 CU x 8
// exactly -> the ONLY shape with both m=2 and 8 waves/CU: 256 blocks x 512 thr
// (8 waves), q-tile = 256 rows. Causal pairing INTRA-block: tile p then 7-p ->
// every block exactly (4p+4)+(32-4p) = 36 iterations; 1 block/CU, no dispatch
// assumptions (all blocks identical). K/V double-buffered (72KB LDS), one barrier
// per iteration, write-late staging (R3-verified scheme). Compute core = R0's
// verified m=2 path: K-frags and V-frags read once, feed both m sub-tiles.
__global__ __launch_bounds__(512, 2) void fattn_main(
    const float* __restrict__ Q,
    const ushort_t* __restrict__ Kb,
    const ushort_t* __restrict__ VTb,
    float* __restrict__ O)
{
    constexpr float K1 = 0.18033688011112042f;   // 0.125 * log2(e)
    constexpr float SHIFT = 12.0f;               // static softmax shift (no running max)
    __shared__ ushort_t KT[2][64 * 72];          // K tiles   [buf][s][e]   18 KB
    __shared__ ushort_t VT[2][64 * 72];          // V^T tiles [buf][d][s]   18 KB
    __shared__ ushort_t P [8][2][16 * 72];       // per (wave,m): 16 q-rows x 64 s  36 KB

    const int bx = blockIdx.x;
    const int bh = bx & 31;                      // bh%8 == bx%8 -> 4 bh per XCD (L2 reuse)
    const int p0 = bx >> 5;                      // 0..7: q-tile pair (p0, 7-p0)
    const int b = bh >> 4, h = bh & 15;
    const int itA = 4 * p0 + 4;                  // iterations in phase A (tile p0)

    const int wave = threadIdx.x >> 6;           // 0..7
    const int lane = threadIdx.x & 63;
    const int l15  = lane & 15;
    const int quad = lane >> 4;

    const ushort_t* kb  = Kb  + bh * (2048 * 64);
    const ushort_t* vtb = VTb + bh * (64 * 2048);
    const float*    qb  = Q + b * (2048 * 1024) + h * 64;
    float*          ob  = O + b * (2048 * 1024) + h * 64;

    const s8v ones = {0x3F80, 0x3F80, 0x3F80, 0x3F80, 0x3F80, 0x3F80, 0x3F80, 0x3F80};
    const f4 zero4 = {0.f, 0.f, 0.f, 0.f};

    // staging: 512 threads x 16B per tile (8KB K + 8KB V per s-tile)
    const int sr = threadIdx.x >> 3;             // row 0..63 (s for K, d for V)
    const int sc = (threadIdx.x & 7) * 8;        // col 0,8,..,56 (ushort units)

    int qr0 = p0 * 256;                          // current phase's q-tile base row

    s8v aq[2][2];                                // Q frags: rows qr0 + wave*32 + m*16 + l15
    f4 oacc[2][4];
    f4 lsum[2];

    auto loadQ = [&](int qr) {
        #pragma unroll
        for (int m = 0; m < 2; ++m) {
            const float* qrow = qb + (qr + wave * 32 + m * 16 + l15) * 1024;
            #pragma unroll
            for (int ks = 0; ks < 2; ++ks) {
                f4 x = *(const f4*)(qrow + ks * 32 + quad * 8);
                f4 y = *(const f4*)(qrow + ks * 32 + quad * 8 + 4);
                #pragma unroll
                for (int j = 0; j < 4; ++j) {
                    aq[m][ks][j]     = (short)f2bf(x[j]);
                    aq[m][ks][j + 4] = (short)f2bf(y[j]);
                }
            }
        }
    };
    auto zeroAcc = [&]() {
        #pragma unroll
        for (int m = 0; m < 2; ++m) {
            lsum[m] = zero4;
            #pragma unroll
            for (int d = 0; d < 4; ++d) oacc[m][d] = zero4;
        }
    };
    auto storeO = [&](int qr) {
        #pragma unroll
        for (int m = 0; m < 2; ++m)
            #pragma unroll
            for (int r = 0; r < 4; ++r) {
                const float inv = 1.0f / lsum[m][r];
                const int row = qr + wave * 32 + m * 16 + quad * 4 + r;
                #pragma unroll
                for (int dd = 0; dd < 4; ++dd)
                    ob[row * 1024 + dd * 16 + l15] = oacc[m][dd][r] * inv;
            }
    };

    loadQ(qr0);
    zeroAcc();

    // ---- prologue: stage s-tile 0 into buffer 0, publish ----
    {
        s8v k0 = *(const s8v*)(kb + sr * 64 + sc);
        s8v v0 = *(const s8v*)(vtb + sr * 2048 + sc);
        *(s8v*)&KT[0][sr * 72 + sc] = k0;
        *(s8v*)&VT[0][sr * 72 + sc] = v0;
    }
    __syncthreads();

    const ushort_t* ktr = KT[0];  const ushort_t* vtr = VT[0];   // read buffers
    ushort_t*       ktw = KT[1];  ushort_t*       vtw = VT[1];   // write buffers

    for (int n = 0; n < 36; ++n) {
        // ---- issue next-tile global loads EARLY (latency hides under compute) ----
        s8v gK2, gV2;
        if (n < 35) {
            const int sn1 = (n + 1 < itA) ? (n + 1) : (n + 1 - itA);  // phase B restarts at 0
            gK2 = *(const s8v*)(kb + (sn1 * 64 + sr) * 64 + sc);
            gV2 = *(const s8v*)(vtb + sr * 2048 + sn1 * 64 + sc);
        }

        const int sn   = (n < itA) ? n : (n - itA);
        const int tcur = (n < itA) ? p0 : (7 - p0);
        const bool diag = (sn >= 4 * tcur);        // last 4 s-tiles of each phase
        const int n0 = sn * 64;

        // ---- QK^T from LDS (S^T = K*Q^T): K-frags read once, feed both m ----
        f4 st[2][4];
        __builtin_amdgcn_s_setprio(1);
        #pragma unroll
        for (int tq = 0; tq < 4; ++tq) {
            const s8v bk0 = *(const s8v*)&ktr[(tq * 16 + l15) * 72 + quad * 8];
            const s8v bk1 = *(const s8v*)&ktr[(tq * 16 + l15) * 72 + 32 + quad * 8];
            #pragma unroll
            for (int m = 0; m < 2; ++m) {
                f4 a = __builtin_amdgcn_mfma_f32_16x16x32_bf16(bk0, aq[m][0], zero4, 0, 0, 0);
                st[m][tq] = __builtin_amdgcn_mfma_f32_16x16x32_bf16(bk1, aq[m][1], a, 0, 0, 0);
            }
        }
        __builtin_amdgcn_s_setprio(0);

        // ---- exp2 + pack + P write (per-(wave,m) private slot, no barrier) ----
        #pragma unroll
        for (int m = 0; m < 2; ++m) {
            ushort_t* Pm = P[wave][m];
            #pragma unroll
            for (int tq = 0; tq < 4; ++tq) {
                float pv4[4];
                #pragma unroll
                for (int r = 0; r < 4; ++r) {
                    float x = __builtin_fmaf(st[m][tq][r], K1, -SHIFT);
                    if (diag) {
                        const int gj = n0 + tq * 16 + quad * 4 + r;          // s-col
                        const int gi = qr0 + wave * 32 + m * 16 + l15;       // q-row
                        if (gj > gi) x = -INFINITY;
                    }
                    pv4[r] = __builtin_exp2f(x);
                }
                u2v pk;
                pk[0] = pack_hi16(pv4[0], pv4[1]);
                pk[1] = pack_hi16(pv4[2], pv4[3]);
                *(u2v*)&Pm[l15 * 72 + tq * 16 + quad * 4] = pk;
            }
        }

        // ---- PV + rowsum-via-ones-MFMA; V-frags read once, feed both m ----
        #pragma unroll
        for (int ks = 0; ks < 2; ++ks) {
            s8v bvv[4];
            #pragma unroll
            for (int dd = 0; dd < 4; ++dd)
                bvv[dd] = *(const s8v*)&vtr[(dd * 16 + l15) * 72 + ks * 32 + quad * 8];
            #pragma unroll
            for (int m = 0; m < 2; ++m) {
                const s8v ap = *(const s8v*)&P[wave][m][l15 * 72 + ks * 32 + quad * 8];
                __builtin_amdgcn_s_setprio(1);
                lsum[m] = __builtin_amdgcn_mfma_f32_16x16x32_bf16(ap, ones, lsum[m], 0, 0, 0);
                #pragma unroll
                for (int dd = 0; dd < 4; ++dd)
                    oacc[m][dd] = __builtin_amdgcn_mfma_f32_16x16x32_bf16(ap, bvv[dd], oacc[m][dd], 0, 0, 0);
                __builtin_amdgcn_s_setprio(0);
            }
        }

        // ---- write-late: commit tile n+1 into the other buffer.
        // Its readers (iteration n-1) finished before the previous barrier -> safe.
        if (n < 35) {
            *(s8v*)&ktw[sr * 72 + sc] = gK2;
            *(s8v*)&vtw[sr * 72 + sc] = gV2;
        }

        __syncthreads();   // single barrier: publishes tile n+1, closes iteration n

        { ushort_t* t0 = (ushort_t*)ktr; ktr = ktw; ktw = t0; }
        { ushort_t* t1 = (ushort_t*)vtr; vtr = vtw; vtw = t1; }

        // ---- phase boundary: finish tile p0, switch to tile 7-p0 ----
        if (n == itA - 1) {
            storeO(qr0);
            qr0 = (7 - p0) * 256;
            loadQ(qr0);
            zeroAcc();
        }
    }

    // ---- epilogue: waves own disjoint q-rows -> direct store, no merge ----
    storeO(qr0);
}

// ---------------- fallback (R2, known-correct) if workspace too small ----------------
#define PSTR 72
__global__ __launch_bounds__(256) void fattn_fallback(
    const float* __restrict__ Q, const float* __restrict__ K,
    const float* __restrict__ V, float* __restrict__ O)
{
    constexpr int strL = 1024, strB = 2048 * strL;
    const float scale = 0.125f;
    __shared__ ushort_t KT[64 * PSTR];
    __shared__ ushort_t VT[64 * PSTR];
    __shared__ ushort_t P[4][16 * PSTR];
    const int bh = blockIdx.x & 31;
    const int b = bh >> 4, h = bh & 15;
    const int im = 31 - (blockIdx.x >> 5);
    const int q0 = im * 64;
    const int tid = threadIdx.x, wave = tid >> 6, lane = tid & 63;
    const int l15 = lane & 15, quad = lane >> 4;
    const float* qbase = Q + b*strB + (q0 + wave*16 + l15)*strL + h*64;
    s8v aq0, aq1;
    {
        f4 q0v = *(const f4*)(qbase + quad*8);
        f4 q1v = *(const f4*)(qbase + quad*8 + 4);
        f4 q2v = *(const f4*)(qbase + 32 + quad*8);
        f4 q3v = *(const f4*)(qbase + 32 + quad*8 + 4);
        #pragma unroll
        for (int j = 0; j < 4; ++j) {
            aq0[j] = (short)f2bf(q0v[j]); aq0[j+4] = (short)f2bf(q1v[j]);
            aq1[j] = (short)f2bf(q2v[j]); aq1[j+4] = (short)f2bf(q3v[j]);
        }
    }
    const f4 zero4 = {0.f,0.f,0.f,0.f};
    f4 oacc[4]; float m_prev[4], lsum[4];
    #pragma unroll
    for (int d = 0; d < 4; ++d) oacc[d] = zero4;
    #pragma unroll
    for (int r = 0; r < 4; ++r) { m_prev[r] = -INFINITY; lsum[r] = 0.0f; }
    const float* kh = K + b*strB + h*64;
    const float* vh = V + b*strB + h*64;
    for (int it = 0; it <= im; ++it) {
        const int n0 = it * 64;
        __syncthreads();
        {
            const float* krow = kh + (n0 + lane)*strL + wave*16;
            f4 k0 = *(const f4*)(krow); f4 k1 = *(const f4*)(krow+4);
            f4 k2 = *(const f4*)(krow+8); f4 k3 = *(const f4*)(krow+12);
            s8v kb0, kb1;
            #pragma unroll
            for (int j = 0; j < 4; ++j) {
                kb0[j] = (short)f2bf(k0[j]); kb0[j+4] = (short)f2bf(k1[j]);
                kb1[j] = (short)f2bf(k2[j]); kb1[j+4] = (short)f2bf(k3[j]);
            }
            *(s8v*)&KT[lane*PSTR + wave*16] = kb0;
            *(s8v*)&KT[lane*PSTR + wave*16 + 8] = kb1;
            const float* vrow = vh + (n0 + lane)*strL + wave*16;
            f4 v0 = *(const f4*)(vrow); f4 v1 = *(const f4*)(vrow+4);
            f4 v2 = *(const f4*)(vrow+8); f4 v3 = *(const f4*)(vrow+12);
            #pragma unroll
            for (int j = 0; j < 4; ++j) {
                VT[(wave*16 + j)*PSTR + lane] = f2bf(v0[j]);
                VT[(wave*16 + 4 + j)*PSTR + lane] = f2bf(v1[j]);
                VT[(wave*16 + 8 + j)*PSTR + lane] = f2bf(v2[j]);
                VT[(wave*16 + 12 + j)*PSTR + lane] = f2bf(v3[j]);
            }
        }
        __syncthreads();
        f4 sacc[4];
        #pragma unroll
        for (int t = 0; t < 4; ++t) {
            sacc[t] = zero4;
            const s8v bk0 = *(const s8v*)&KT[(t*16 + l15)*PSTR + quad*8];
            const s8v bk1 = *(const s8v*)&KT[(t*16 + l15)*PSTR + 32 + quad*8];
            sacc[t] = __builtin_amdgcn_mfma_f32_16x16x32_bf16(aq0, bk0, sacc[t], 0, 0, 0);
            sacc[t] = __builtin_amdgcn_mfma_f32_16x16x32_bf16(aq1, bk1, sacc[t], 0, 0, 0);
        }
        const bool diag = (it == im);
        float sv[4][4], rmax[4];
        #pragma unroll
        for (int r = 0; r < 4; ++r) rmax[r] = -INFINITY;
        #pragma unroll
        for (int t = 0; t < 4; ++t)
            #pragma unroll
            for (int r = 0; r < 4; ++r) {
                float x = sacc[t][r] * scale;
                if (diag) {
                    const int gi = wave*16 + quad*4 + r;
                    const int gj = t*16 + l15;
                    if (gj > gi) x = -INFINITY;
                }
                sv[t][r] = x; rmax[r] = fmaxf(rmax[r], x);
            }
        #pragma unroll
        for (int off = 8; off >= 1; off >>= 1)
            #pragma unroll
            for (int r = 0; r < 4; ++r)
                rmax[r] = fmaxf(rmax[r], __shfl_xor(rmax[r], off, 64));
        float mnew[4], alpha[4], rsum[4];
        #pragma unroll
        for (int r = 0; r < 4; ++r) {
            mnew[r] = fmaxf(m_prev[r], rmax[r]);
            alpha[r] = __expf(m_prev[r] - mnew[r]);
            m_prev[r] = mnew[r]; rsum[r] = 0.f;
        }
        #pragma unroll
        for (int t = 0; t < 4; ++t)
            #pragma unroll
            for (int r = 0; r < 4; ++r) {
                const float p = __expf(sv[t][r] - mnew[r]);
                rsum[r] += p;
                P[wave][(quad*4 + r)*PSTR + t*16 + l15] = f2bf(p);
            }
        #pragma unroll
        for (int off = 8; off >= 1; off >>= 1)
            #pragma unroll
            for (int r = 0; r < 4; ++r)
                rsum[r] += __shfl_xor(rsum[r], off, 64);
        #pragma unroll
        for (int r = 0; r < 4; ++r) lsum[r] = alpha[r]*lsum[r] + rsum[r];
        #pragma unroll
        for (int d = 0; d < 4; ++d)
            #pragma unroll
            for (int r = 0; r < 4; ++r) oacc[d][r] *= alpha[r];
        #pragma unroll
        for (int ks = 0; ks < 2; ++ks) {
            const s8v ap = *(const s8v*)&P[wave][l15*PSTR + ks*32 + quad*8];
            #pragma unroll
            for (int d = 0; d < 4; ++d) {
                const s8v bvv = *(const s8v*)&VT[(d*16 + l15)*PSTR + ks*32 + quad*8];
                oacc[d] = __builtin_amdgcn_mfma_f32_16x16x32_bf16(ap, bvv, oacc[d], 0, 0, 0);
            }
        }
    }
    float* obase = O + b*strB + h*64;
    #pragma unroll
    for (int r = 0; r < 4; ++r) {
        const float inv = 1.0f / lsum[r];
        const int gi = q0 + wave*16 + quad*4 + r;
        #pragma unroll
        for (int d = 0; d < 4; ++d)
            obase[gi*strL + d*16 + l15] = oacc[d][r] * inv;
    }
}

extern "C" void kernel_launch(void* const* d_in, const int* in_sizes, int n_in,
                              void* d_out, int out_size, void* d_ws, size_t ws_size,
                              hipStream_t stream) {
    const float* Q = (const float*)d_in[0];
    const float* K = (const float*)d_in[1];
    const float* V = (const float*)d_in[2];
    float* O = (float*)d_out;
    const size_t NEED = 2ull * 4194304ull * 2ull;   // Kb + VT, bf16: 16.78 MB
    if (ws_size >= NEED) {
        ushort_t* Kb = (ushort_t*)d_ws;
        ushort_t* VT = Kb + 4194304;
        prep_kv<<<3072, 256, 0, stream>>>(K, V, Kb, VT);
        fattn_main<<<256, 512, 0, stream>>>(Q, Kb, VT, O);
    } else {
        fattn_fallback<<<1024, 256, 0, stream>>>(Q, K, V, O);
    }
}

// Round 6
// 151.089 us; speedup vs baseline: 1.2636x; 1.2636x over previous
//
#include <hip/hip_runtime.h>

typedef unsigned short ushort_t;
typedef __attribute__((ext_vector_type(8))) short s8v;      // 8 bf16 bits = MFMA A/B frag
typedef __attribute__((ext_vector_type(2))) unsigned u2v;   // packed 4 bf16 (8B LDS write)
typedef __attribute__((ext_vector_type(4))) unsigned u4v;   // 4 u32 = 8 bf16
typedef __attribute__((ext_vector_type(4))) float f4;       // float4 / MFMA C/D frag

__device__ __forceinline__ ushort_t f2bf(float x) {      // RNE fp32->bf16
    unsigned u = __builtin_bit_cast(unsigned, x);
    return (ushort_t)((u + 0x7FFFu + ((u >> 16) & 1u)) >> 16);
}
__device__ __forceinline__ unsigned pack_hi16(float lo, float hi) {  // {bf16(hi),bf16(lo)} trunc
    unsigned a = __builtin_bit_cast(unsigned, lo);
    unsigned b = __builtin_bit_cast(unsigned, hi);
    return (a >> 16) | (b & 0xFFFF0000u);
}

// ---- fused pre-pass: blocks 0..2047 K-convert, 2048..3071 V-transpose (unchanged) ----
__global__ __launch_bounds__(256) void prep_kv(const float* __restrict__ K,
                                               const float* __restrict__ V,
                                               ushort_t* __restrict__ Kb,
                                               ushort_t* __restrict__ VT) {
    __shared__ ushort_t T[64 * 72];
    if (blockIdx.x < 2048) {
        const int gid = blockIdx.x * 256 + threadIdx.x;
        const int e = (gid & 7) * 8;
        const int h = (gid >> 3) & 15;
        const int s = (gid >> 7) & 2047;
        const int b = gid >> 18;
        const float* src = K + (((b * 2048 + s) * 16 + h) * 64 + e);
        f4 a = *(const f4*)src;
        f4 c = *(const f4*)(src + 4);
        s8v o;
        #pragma unroll
        for (int j = 0; j < 4; ++j) { o[j] = (short)f2bf(a[j]); o[j + 4] = (short)f2bf(c[j]); }
        *(s8v*)(Kb + (((b * 16 + h) * 2048 + s) * 64 + e)) = o;
    } else {
        const int v = blockIdx.x - 2048;
        const int s0 = (v & 31) * 64;
        const int h  = (v >> 5) & 15;
        const int b  = v >> 9;
        const int t  = threadIdx.x;
        {
            const int srow = t >> 2, dc = (t & 3) * 16;
            const float* src = V + (((b * 2048 + s0 + srow) * 16 + h) * 64 + dc);
            #pragma unroll
            for (int c = 0; c < 4; ++c) {
                f4 vv = *(const f4*)(src + c * 4);
                #pragma unroll
                for (int j = 0; j < 4; ++j) T[(dc + c * 4 + j) * 72 + srow] = f2bf(vv[j]);
            }
        }
        __syncthreads();
        {
            const int d = t >> 2, sq = (t & 3) * 16;
            ushort_t* dst = VT + (((b * 16 + h) * 64 + d) * 2048 + s0 + sq);
            *(s8v*)(dst)     = *(const s8v*)(&T[d * 72 + sq]);
            *(s8v*)(dst + 8) = *(const s8v*)(&T[d * 72 + sq + 8]);
        }
    }
}

// ---------------- main: LDS flash attention, IN-REGISTER P (no LDS round-trip) --------
// 512 blocks x 256 thr (4 waves x 16 q-rows), paired causal q-tiles (p, 31-p) = 33
// iters/block, 2 identical blocks/CU, 8 waves/CU flat — the verified R1/R3 shape
// (54.6-55.7us). R5's clean data (8w/CU, LDS 47%, VALU 53%, MFMA 18% — nothing
// saturated) shows the bind is the per-iteration serial chain. Biggest removable
// link: P's LDS write->lgkmcnt->read between softmax and PV.
// NEW: P never touches LDS. QK output at lane(l15,quad) is S[row=l15][s=16t+4q+r];
// PV's A-frag needs P[row=l15][s=32ks+8q+j] — a permutation within each 4-lane
// group {l15,+16,+32,+48}. After bf16-pair packing (8 u32 words: w[2t+i] =
// pack(st[t][2i],st[t][2i+1])), a 2-stage butterfly of v_permlane32_swap_b32 +
// v_permlane16_swap_b32 (gfx950) on pairs (w0,w2),(w1,w3),(w4,w6),(w5,w7) lands
// ap_ks0={w0,w1,w2,w3}, ap_ks1={w4,w5,w6,w7} at every lane. Verified mapping:
// src lane(l15,q) word pack(st[t][2i],st[t][2i+1]) holds s=16t+4q+{2i,2i+1};
// dest lane(l15,qd) frag elem j (k=8qd+j, s=32ks+8qd+j) comes from
// q_src=(2qd+(j>>2))&3, t=2ks+(qd>>1) — exactly what the butterfly routes.
// Removes 4 ds_writes + 2 ds_reads + the lgkm wait per wave-iter; frees P's LDS.
__global__ __launch_bounds__(256, 2) void fattn_main(
    const float* __restrict__ Q,
    const ushort_t* __restrict__ Kb,
    const ushort_t* __restrict__ VTb,
    float* __restrict__ O)
{
    constexpr float K1 = 0.18033688011112042f;   // 0.125 * log2(e)
    constexpr float SHIFT = 12.0f;               // static softmax shift (no running max)
    __shared__ ushort_t KT0[64 * 72];            // K tile   [s][e], buffer 0
    __shared__ ushort_t KT1[64 * 72];            // K tile   [s][e], buffer 1
    __shared__ ushort_t VT0[64 * 72];            // V^T tile [d][s], buffer 0
    __shared__ ushort_t VT1[64 * 72];            // V^T tile [d][s], buffer 1

    const int bx = blockIdx.x;
    const int bh = bx & 31;                      // bh%8 == bx%8 -> 4 bh per XCD (L2 reuse)
    const int p  = bx >> 5;                      // 0..15: q-tile pair (p, 31-p)
    const int b = bh >> 4, h = bh & 15;

    const int wave = threadIdx.x >> 6;           // 0..3
    const int lane = threadIdx.x & 63;
    const int l15  = lane & 15;
    const int quad = lane >> 4;

    const ushort_t* kb  = Kb  + bh * (2048 * 64);
    const ushort_t* vtb = VTb + bh * (64 * 2048);
    const float*    qb  = Q + b * (2048 * 1024) + h * 64;
    float*          ob  = O + b * (2048 * 1024) + h * 64;

    const s8v ones = {0x3F80, 0x3F80, 0x3F80, 0x3F80, 0x3F80, 0x3F80, 0x3F80, 0x3F80};
    const f4 zero4 = {0.f, 0.f, 0.f, 0.f};

    // staging coordinates: each of 256 threads owns one 16-col chunk of one row
    const int sr = threadIdx.x >> 2;             // row 0..63 (s for K, d for V)
    const int sc = (threadIdx.x & 3) << 4;       // col 0,16,32,48

    int qr0 = p * 64;                            // current phase's q-tile base row

    s8v aq[2];                                   // Q frags: wave's rows qr0 + wave*16 + l15
    f4 oacc[4];
    f4 lsum;

    auto loadQ = [&](int qr) {
        const float* qrow = qb + (qr + wave * 16 + l15) * 1024;
        #pragma unroll
        for (int ks = 0; ks < 2; ++ks) {
            f4 x = *(const f4*)(qrow + ks * 32 + quad * 8);
            f4 y = *(const f4*)(qrow + ks * 32 + quad * 8 + 4);
            #pragma unroll
            for (int j = 0; j < 4; ++j) {
                aq[ks][j]     = (short)f2bf(x[j]);
                aq[ks][j + 4] = (short)f2bf(y[j]);
            }
        }
    };
    auto zeroAcc = [&]() {
        lsum = zero4;
        #pragma unroll
        for (int d = 0; d < 4; ++d) oacc[d] = zero4;
    };
    auto storeO = [&](int qr) {
        #pragma unroll
        for (int r = 0; r < 4; ++r) {
            const float inv = 1.0f / lsum[r];
            const int row = qr + wave * 16 + quad * 4 + r;
            #pragma unroll
            for (int dd = 0; dd < 4; ++dd)
                ob[row * 1024 + dd * 16 + l15] = oacc[dd][r] * inv;
        }
    };

    loadQ(qr0);
    zeroAcc();

    // ---- prologue: stage s-tile 0 into buffer 0, publish ----
    {
        const ushort_t* ksrc = kb + sr * 64 + sc;
        const ushort_t* vsrc = vtb + sr * 2048 + sc;
        s8v k0 = *(const s8v*)(ksrc);
        s8v k1 = *(const s8v*)(ksrc + 8);
        s8v v0 = *(const s8v*)(vsrc);
        s8v v1 = *(const s8v*)(vsrc + 8);
        *(s8v*)&KT0[sr * 72 + sc]     = k0;
        *(s8v*)&KT0[sr * 72 + sc + 8] = k1;
        *(s8v*)&VT0[sr * 72 + sc]     = v0;
        *(s8v*)&VT0[sr * 72 + sc + 8] = v1;
    }
    __syncthreads();

    ushort_t* ktr = KT0;  ushort_t* vtr = VT0;   // read buffers (tile n)
    ushort_t* ktw = KT1;  ushort_t* vtw = VT1;   // write buffers (tile n+1)

    for (int n = 0; n < 33; ++n) {
        // ---- issue next-tile global loads EARLY (latency hides under compute) ----
        s8v gK2[2], gV2[2];
        if (n < 32) {
            const int sn = (n + 1 <= p) ? (n + 1) : (n - p);    // phase B restarts at 0
            const ushort_t* ksrc = kb + (sn * 64 + sr) * 64 + sc;
            const ushort_t* vsrc = vtb + sr * 2048 + sn * 64 + sc;
            gK2[0] = *(const s8v*)(ksrc);    gK2[1] = *(const s8v*)(ksrc + 8);
            gV2[0] = *(const s8v*)(vsrc);    gV2[1] = *(const s8v*)(vsrc + 8);
        }

        const int s_cur = (n <= p) ? n : (n - p - 1);
        const int n0 = s_cur * 64;
        const bool diag = (n == p) || (n == 32);   // diagonal tile of phase A / phase B

        // ---- QK^T from LDS (S^T = K*Q^T): lane col = q-row, rows = s-cols ----
        f4 st[4];
        __builtin_amdgcn_s_setprio(1);
        #pragma unroll
        for (int t = 0; t < 4; ++t) {
            const s8v bk0 = *(const s8v*)&ktr[(t * 16 + l15) * 72 + quad * 8];
            const s8v bk1 = *(const s8v*)&ktr[(t * 16 + l15) * 72 + 32 + quad * 8];
            f4 a = __builtin_amdgcn_mfma_f32_16x16x32_bf16(bk0, aq[0], zero4, 0, 0, 0);
            st[t] = __builtin_amdgcn_mfma_f32_16x16x32_bf16(bk1, aq[1], a, 0, 0, 0);
        }
        __builtin_amdgcn_s_setprio(0);

        // ---- softmax (exp2 with static shift) + bf16-pair pack, all in registers ----
        unsigned w[8];
        #pragma unroll
        for (int t = 0; t < 4; ++t) {
            float pv4[4];
            #pragma unroll
            for (int r = 0; r < 4; ++r) {
                float x = __builtin_fmaf(st[t][r], K1, -SHIFT);
                if (diag) {
                    const int gj = n0 + t * 16 + quad * 4 + r;      // s-col
                    const int gi = qr0 + wave * 16 + l15;           // q-row
                    if (gj > gi) x = -INFINITY;
                }
                pv4[r] = __builtin_exp2f(x);
            }
            w[t * 2]     = pack_hi16(pv4[0], pv4[1]);
            w[t * 2 + 1] = pack_hi16(pv4[2], pv4[3]);
        }

        // ---- in-register P redistribution: 2-stage butterfly within 4-lane groups.
        // stage 1: lanes 0-31 <-> 32-63 ; stage 2: 16-groups. After this:
        // ap_ks0 = {w0,w1,w2,w3}, ap_ks1 = {w4,w5,w6,w7} (A-frag layout for PV).
        asm volatile("v_permlane32_swap_b32 %0, %1" : "+v"(w[0]), "+v"(w[2]));
        asm volatile("v_permlane32_swap_b32 %0, %1" : "+v"(w[1]), "+v"(w[3]));
        asm volatile("v_permlane32_swap_b32 %0, %1" : "+v"(w[4]), "+v"(w[6]));
        asm volatile("v_permlane32_swap_b32 %0, %1" : "+v"(w[5]), "+v"(w[7]));
        asm volatile("v_permlane16_swap_b32 %0, %1" : "+v"(w[0]), "+v"(w[2]));
        asm volatile("v_permlane16_swap_b32 %0, %1" : "+v"(w[1]), "+v"(w[3]));
        asm volatile("v_permlane16_swap_b32 %0, %1" : "+v"(w[4]), "+v"(w[6]));
        asm volatile("v_permlane16_swap_b32 %0, %1" : "+v"(w[5]), "+v"(w[7]));

        u4v a0v = {w[0], w[1], w[2], w[3]};
        u4v a1v = {w[4], w[5], w[6], w[7]};
        const s8v ap0 = __builtin_bit_cast(s8v, a0v);
        const s8v ap1 = __builtin_bit_cast(s8v, a1v);

        // ---- PV + rowsum-via-ones-MFMA; V frags from LDS, P from registers ----
        #pragma unroll
        for (int ks = 0; ks < 2; ++ks) {
            s8v bvv[4];
            #pragma unroll
            for (int dd = 0; dd < 4; ++dd)
                bvv[dd] = *(const s8v*)&vtr[(dd * 16 + l15) * 72 + ks * 32 + quad * 8];
            const s8v ap = ks ? ap1 : ap0;
            __builtin_amdgcn_s_setprio(1);
            lsum = __builtin_amdgcn_mfma_f32_16x16x32_bf16(ap, ones, lsum, 0, 0, 0);
            #pragma unroll
            for (int dd = 0; dd < 4; ++dd)
                oacc[dd] = __builtin_amdgcn_mfma_f32_16x16x32_bf16(ap, bvv[dd], oacc[dd], 0, 0, 0);
            __builtin_amdgcn_s_setprio(0);
        }

        // ---- write-late: commit prefetched tile n+1 into the other buffer.
        // Its readers (iter n-1) all finished before the previous barrier -> safe.
        if (n < 32) {
            *(s8v*)&ktw[sr * 72 + sc]     = gK2[0];
            *(s8v*)&ktw[sr * 72 + sc + 8] = gK2[1];
            *(s8v*)&vtw[sr * 72 + sc]     = gV2[0];
            *(s8v*)&vtw[sr * 72 + sc + 8] = gV2[1];
        }

        __syncthreads();   // single barrier: publishes tile n+1, closes iteration n

        { ushort_t* t0 = ktr; ktr = ktw; ktw = t0; }
        { ushort_t* t1 = vtr; vtr = vtw; vtw = t1; }

        // ---- phase boundary: finish tile p, switch to tile 31-p ----
        if (n == p) {
            storeO(qr0);
            qr0 = (31 - p) * 64;
            loadQ(qr0);
            zeroAcc();
        }
    }

    // ---- epilogue: waves own disjoint q-rows -> direct store, no merge ----
    storeO(qr0);
}

// ---------------- fallback (R2, known-correct) if workspace too small ----------------
#define PSTR 72
__global__ __launch_bounds__(256) void fattn_fallback(
    const float* __restrict__ Q, const float* __restrict__ K,
    const float* __restrict__ V, float* __restrict__ O)
{
    constexpr int strL = 1024, strB = 2048 * strL;
    const float scale = 0.125f;
    __shared__ ushort_t KT[64 * PSTR];
    __shared__ ushort_t VT[64 * PSTR];
    __shared__ ushort_t P[4][16 * PSTR];
    const int bh = blockIdx.x & 31;
    const int b = bh >> 4, h = bh & 15;
    const int im = 31 - (blockIdx.x >> 5);
    const int q0 = im * 64;
    const int tid = threadIdx.x, wave = tid >> 6, lane = tid & 63;
    const int l15 = lane & 15, quad = lane >> 4;
    const float* qbase = Q + b*strB + (q0 + wave*16 + l15)*strL + h*64;
    s8v aq0, aq1;
    {
        f4 q0v = *(const f4*)(qbase + quad*8);
        f4 q1v = *(const f4*)(qbase + quad*8 + 4);
        f4 q2v = *(const f4*)(qbase + 32 + quad*8);
        f4 q3v = *(const f4*)(qbase + 32 + quad*8 + 4);
        #pragma unroll
        for (int j = 0; j < 4; ++j) {
            aq0[j] = (short)f2bf(q0v[j]); aq0[j+4] = (short)f2bf(q1v[j]);
            aq1[j] = (short)f2bf(q2v[j]); aq1[j+4] = (short)f2bf(q3v[j]);
        }
    }
    const f4 zero4 = {0.f,0.f,0.f,0.f};
    f4 oacc[4]; float m_prev[4], lsum[4];
    #pragma unroll
    for (int d = 0; d < 4; ++d) oacc[d] = zero4;
    #pragma unroll
    for (int r = 0; r < 4; ++r) { m_prev[r] = -INFINITY; lsum[r] = 0.0f; }
    const float* kh = K + b*strB + h*64;
    const float* vh = V + b*strB + h*64;
    for (int it = 0; it <= im; ++it) {
        const int n0 = it * 64;
        __syncthreads();
        {
            const float* krow = kh + (n0 + lane)*strL + wave*16;
            f4 k0 = *(const f4*)(krow); f4 k1 = *(const f4*)(krow+4);
            f4 k2 = *(const f4*)(krow+8); f4 k3 = *(const f4*)(krow+12);
            s8v kb0, kb1;
            #pragma unroll
            for (int j = 0; j < 4; ++j) {
                kb0[j] = (short)f2bf(k0[j]); kb0[j+4] = (short)f2bf(k1[j]);
                kb1[j] = (short)f2bf(k2[j]); kb1[j+4] = (short)f2bf(k3[j]);
            }
            *(s8v*)&KT[lane*PSTR + wave*16] = kb0;
            *(s8v*)&KT[lane*PSTR + wave*16 + 8] = kb1;
            const float* vrow = vh + (n0 + lane)*strL + wave*16;
            f4 v0 = *(const f4*)(vrow); f4 v1 = *(const f4*)(vrow+4);
            f4 v2 = *(const f4*)(vrow+8); f4 v3 = *(const f4*)(vrow+12);
            #pragma unroll
            for (int j = 0; j < 4; ++j) {
                VT[(wave*16 + j)*PSTR + lane] = f2bf(v0[j]);
                VT[(wave*16 + 4 + j)*PSTR + lane] = f2bf(v1[j]);
                VT[(wave*16 + 8 + j)*PSTR + lane] = f2bf(v2[j]);
                VT[(wave*16 + 12 + j)*PSTR + lane] = f2bf(v3[j]);
            }
        }
        __syncthreads();
        f4 sacc[4];
        #pragma unroll
        for (int t = 0; t < 4; ++t) {
            sacc[t] = zero4;
            const s8v bk0 = *(const s8v*)&KT[(t*16 + l15)*PSTR + quad*8];
            const s8v bk1 = *(const s8v*)&KT[(t*16 + l15)*PSTR + 32 + quad*8];
            sacc[t] = __builtin_amdgcn_mfma_f32_16x16x32_bf16(aq0, bk0, sacc[t], 0, 0, 0);
            sacc[t] = __builtin_amdgcn_mfma_f32_16x16x32_bf16(aq1, bk1, sacc[t], 0, 0, 0);
        }
        const bool diag = (it == im);
        float sv[4][4], rmax[4];
        #pragma unroll
        for (int r = 0; r < 4; ++r) rmax[r] = -INFINITY;
        #pragma unroll
        for (int t = 0; t < 4; ++t)
            #pragma unroll
            for (int r = 0; r < 4; ++r) {
                float x = sacc[t][r] * scale;
                if (diag) {
                    const int gi = wave*16 + quad*4 + r;
                    const int gj = t*16 + l15;
                    if (gj > gi) x = -INFINITY;
                }
                sv[t][r] = x; rmax[r] = fmaxf(rmax[r], x);
            }
        #pragma unroll
        for (int off = 8; off >= 1; off >>= 1)
            #pragma unroll
            for (int r = 0; r < 4; ++r)
                rmax[r] = fmaxf(rmax[r], __shfl_xor(rmax[r], off, 64));
        float mnew[4], alpha[4], rsum[4];
        #pragma unroll
        for (int r = 0; r < 4; ++r) {
            mnew[r] = fmaxf(m_prev[r], rmax[r]);
            alpha[r] = __expf(m_prev[r] - mnew[r]);
            m_prev[r] = mnew[r]; rsum[r] = 0.f;
        }
        #pragma unroll
        for (int t = 0; t < 4; ++t)
            #pragma unroll
            for (int r = 0; r < 4; ++r) {
                const float p = __expf(sv[t][r] - mnew[r]);
                rsum[r] += p;
                P[wave][(quad*4 + r)*PSTR + t*16 + l15] = f2bf(p);
            }
        #pragma unroll
        for (int off = 8; off >= 1; off >>= 1)
            #pragma unroll
            for (int r = 0; r < 4; ++r)
                rsum[r] += __shfl_xor(rsum[r], off, 64);
        #pragma unroll
        for (int r = 0; r < 4; ++r) lsum[r] = alpha[r]*lsum[r] + rsum[r];
        #pragma unroll
        for (int d = 0; d < 4; ++d)
            #pragma unroll
            for (int r = 0; r < 4; ++r) oacc[d][r] *= alpha[r];
        #pragma unroll
        for (int ks = 0; ks < 2; ++ks) {
            const s8v ap = *(const s8v*)&P[wave][l15*PSTR + ks*32 + quad*8];
            #pragma unroll
            for (int d = 0; d < 4; ++d) {
                const s8v bvv = *(const s8v*)&VT[(d*16 + l15)*PSTR + ks*32 + quad*8];
                oacc[d] = __builtin_amdgcn_mfma_f32_16x16x32_bf16(ap, bvv, oacc[d], 0, 0, 0);
            }
        }
    }
    float* obase = O + b*strB + h*64;
    #pragma unroll
    for (int r = 0; r < 4; ++r) {
        const float inv = 1.0f / lsum[r];
        const int gi = q0 + wave*16 + quad*4 + r;
        #pragma unroll
        for (int d = 0; d < 4; ++d)
            obase[gi*strL + d*16 + l15] = oacc[d][r] * inv;
    }
}

extern "C" void kernel_launch(void* const* d_in, const int* in_sizes, int n_in,
                              void* d_out, int out_size, void* d_ws, size_t ws_size,
                              hipStream_t stream) {
    const float* Q = (const float*)d_in[0];
    const float* K = (const float*)d_in[1];
    const float* V = (const float*)d_in[2];
    float* O = (float*)d_out;
    const size_t NEED = 2ull * 4194304ull * 2ull;   // Kb + VT, bf16: 16.78 MB
    if (ws_size >= NEED) {
        ushort_t* Kb = (ushort_t*)d_ws;
        ushort_t* VT = Kb + 4194304;
        prep_kv<<<3072, 256, 0, stream>>>(K, V, Kb, VT);
        fattn_main<<<512, 256, 0, stream>>>(Q, Kb, VT, O);
    } else {
        fattn_fallback<<<1024, 256, 0, stream>>>(Q, K, V, O);
    }
}